// Round 1
// baseline (2981.597 us; speedup 1.0000x reference)
//
#include <hip/hip_runtime.h>
#include <math.h>

#define SEQ 4096
#define DMODEL 1024
#define NH 16
#define DK 64

// ---------------------------------------------------------------------------
// GEMM: C[m][n] = sum_k A[m][k] * B[n][k] + bias[n]   (torch Linear: x @ W.T + b)
// A: M x K row-major; B: N x K row-major; C: M x N row-major.
// Tiles: BM=128, BN=64, BK=16. 256 threads; each thread computes 8x4.
// LDS stored k-major (transposed) with +4 pad so fragment reads are b128.
// ---------------------------------------------------------------------------
__global__ __launch_bounds__(256)
void gemm_nt_bias(const float* __restrict__ A, const float* __restrict__ B,
                  const float* __restrict__ bias, float* __restrict__ C,
                  int M, int N, int K)
{
    __shared__ float As[16][132];   // [k][m], pad 128->132 keeps b128 alignment
    __shared__ float Bs[16][68];    // [k][n], pad 64->68

    const int t  = threadIdx.x;
    const int tx = t & 15;          // owns 4 cols (n)
    const int ty = t >> 4;          // owns 8 rows (m)
    const int m0 = blockIdx.y * 128;
    const int n0 = blockIdx.x * 64;

    float acc[8][4] = {};

    for (int k0 = 0; k0 < K; k0 += 16) {
        // A tile 128x16 = 512 float4 loads, 2 per thread, transpose into LDS
        {
            int idx = t;
            #pragma unroll
            for (int p = 0; p < 2; ++p, idx += 256) {
                const int r = idx >> 2, c4 = idx & 3;
                const float4 v = *reinterpret_cast<const float4*>(
                    &A[(size_t)(m0 + r) * K + k0 + c4 * 4]);
                As[c4*4+0][r] = v.x;
                As[c4*4+1][r] = v.y;
                As[c4*4+2][r] = v.z;
                As[c4*4+3][r] = v.w;
            }
        }
        // B tile 64x16 = 256 float4 loads, 1 per thread
        {
            const int r = t >> 2, c4 = t & 3;
            const float4 v = *reinterpret_cast<const float4*>(
                &B[(size_t)(n0 + r) * K + k0 + c4 * 4]);
            Bs[c4*4+0][r] = v.x;
            Bs[c4*4+1][r] = v.y;
            Bs[c4*4+2][r] = v.z;
            Bs[c4*4+3][r] = v.w;
        }
        __syncthreads();
        #pragma unroll
        for (int k = 0; k < 16; ++k) {
            const float4 a0 = *reinterpret_cast<const float4*>(&As[k][ty*8]);
            const float4 a1 = *reinterpret_cast<const float4*>(&As[k][ty*8+4]);
            const float4 bv = *reinterpret_cast<const float4*>(&Bs[k][tx*4]);
            const float a[8] = {a0.x,a0.y,a0.z,a0.w,a1.x,a1.y,a1.z,a1.w};
            const float b[4] = {bv.x,bv.y,bv.z,bv.w};
            #pragma unroll
            for (int i = 0; i < 8; ++i)
                #pragma unroll
                for (int j = 0; j < 4; ++j)
                    acc[i][j] = fmaf(a[i], b[j], acc[i][j]);
        }
        __syncthreads();
    }

    const float4 bb = *reinterpret_cast<const float4*>(&bias[n0 + tx*4]);
    #pragma unroll
    for (int i = 0; i < 8; ++i) {
        float4 o;
        o.x = acc[i][0] + bb.x;
        o.y = acc[i][1] + bb.y;
        o.z = acc[i][2] + bb.z;
        o.w = acc[i][3] + bb.w;
        *reinterpret_cast<float4*>(
            &C[(size_t)(m0 + ty*8 + i) * N + n0 + tx*4]) = o;
    }
}

// ---------------------------------------------------------------------------
// Causal flash attention, fp32. One block = (64 query rows) x (1 head).
// Q,K,V,O are (SEQ, DMODEL) row-major; head h occupies cols [h*DK, h*DK+64).
// 256 threads as 16x16: ty (t>>4) owns 4 query rows, tx (t&15) owns 4
// key-cols (score phase) / 4 output dims (PV phase).
// Online softmax state per row replicated across the 16 tx lanes.
// ---------------------------------------------------------------------------
__global__ __launch_bounds__(256)
void attn_causal(const float* __restrict__ Q, const float* __restrict__ K,
                 const float* __restrict__ V, float* __restrict__ O)
{
    __shared__ float Qt[64][68];  // [d][i]  (transposed: b128 reads in score)
    __shared__ float Kt[64][68];  // [d][j]
    __shared__ float Vs[64][68];  // [j][d]
    __shared__ float Pt[64][68];  // [j][i]  (transposed: b128 reads in PV)

    const int t  = threadIdx.x;
    const int tx = t & 15;
    const int ty = t >> 4;
    const int h  = blockIdx.y;
    const int q0 = blockIdx.x * 64;

    // Load Q tile transposed: 4096 floats = 1024 float4, 4 per thread.
    {
        int idx = t;
        #pragma unroll
        for (int p = 0; p < 4; ++p, idx += 256) {
            const int r = idx >> 4, c4 = idx & 15;
            const float4 v = *reinterpret_cast<const float4*>(
                &Q[(size_t)(q0 + r) * DMODEL + h * DK + c4 * 4]);
            Qt[c4*4+0][r] = v.x;
            Qt[c4*4+1][r] = v.y;
            Qt[c4*4+2][r] = v.z;
            Qt[c4*4+3][r] = v.w;
        }
    }

    float acc[4][4] = {};
    float mrow[4] = {-INFINITY, -INFINITY, -INFINITY, -INFINITY};
    float lrow[4] = {};

    const int ntiles = blockIdx.x + 1;   // causal: kv tiles with j0 <= q0
    for (int tk = 0; tk < ntiles; ++tk) {
        const int j0 = tk * 64;
        __syncthreads();   // previous iteration done with Kt/Vs/Pt (and Qt stores visible on iter 0)
        {
            int idx = t;
            #pragma unroll
            for (int p = 0; p < 4; ++p, idx += 256) {
                const int r = idx >> 4, c4 = idx & 15;
                const float4 kv = *reinterpret_cast<const float4*>(
                    &K[(size_t)(j0 + r) * DMODEL + h * DK + c4 * 4]);
                Kt[c4*4+0][r] = kv.x;
                Kt[c4*4+1][r] = kv.y;
                Kt[c4*4+2][r] = kv.z;
                Kt[c4*4+3][r] = kv.w;
                const float4 vv = *reinterpret_cast<const float4*>(
                    &V[(size_t)(j0 + r) * DMODEL + h * DK + c4 * 4]);
                *reinterpret_cast<float4*>(&Vs[r][c4*4]) = vv;
            }
        }
        __syncthreads();

        // ---- scores: sc[ii][jj] = q(ty*4+ii) . k(tx*4+jj) ----
        float sc[4][4] = {};
        #pragma unroll
        for (int d = 0; d < 64; ++d) {
            const float4 av = *reinterpret_cast<const float4*>(&Qt[d][ty*4]);
            const float4 bv = *reinterpret_cast<const float4*>(&Kt[d][tx*4]);
            const float a[4] = {av.x, av.y, av.z, av.w};
            const float b[4] = {bv.x, bv.y, bv.z, bv.w};
            #pragma unroll
            for (int ii = 0; ii < 4; ++ii)
                #pragma unroll
                for (int jj = 0; jj < 4; ++jj)
                    sc[ii][jj] = fmaf(a[ii], b[jj], sc[ii][jj]);
        }

        // ---- online softmax update (scale = 1/sqrt(64) = 0.125) ----
        #pragma unroll
        for (int ii = 0; ii < 4; ++ii) {
            const int qrow = q0 + ty*4 + ii;
            float mx = -INFINITY;
            #pragma unroll
            for (int jj = 0; jj < 4; ++jj) {
                const int j = j0 + tx*4 + jj;
                const float v = (j <= qrow) ? sc[ii][jj] * 0.125f : -INFINITY;
                sc[ii][jj] = v;
                mx = fmaxf(mx, v);
            }
            mx = fmaxf(mx, __shfl_xor(mx, 1));
            mx = fmaxf(mx, __shfl_xor(mx, 2));
            mx = fmaxf(mx, __shfl_xor(mx, 4));
            mx = fmaxf(mx, __shfl_xor(mx, 8));
            const float mnew  = fmaxf(mrow[ii], mx);     // finite after tile 0 (j=j0<=qrow exists)
            const float alpha = __expf(mrow[ii] - mnew); // first tile: exp(-inf)=0, no NaN
            float rs = 0.f;
            #pragma unroll
            for (int jj = 0; jj < 4; ++jj) {
                const float p = __expf(sc[ii][jj] - mnew);
                Pt[tx*4+jj][ty*4+ii] = p;
                rs += p;
            }
            rs += __shfl_xor(rs, 1);
            rs += __shfl_xor(rs, 2);
            rs += __shfl_xor(rs, 4);
            rs += __shfl_xor(rs, 8);
            lrow[ii] = lrow[ii] * alpha + rs;
            mrow[ii] = mnew;
            #pragma unroll
            for (int dd = 0; dd < 4; ++dd) acc[ii][dd] *= alpha;
        }
        __syncthreads();   // Pt visible to all

        // ---- PV: acc[ii][dd] += sum_j P[ty*4+ii][j] * V[j][tx*4+dd] ----
        #pragma unroll
        for (int j = 0; j < 64; ++j) {
            const float4 av = *reinterpret_cast<const float4*>(&Pt[j][ty*4]);
            const float4 bv = *reinterpret_cast<const float4*>(&Vs[j][tx*4]);
            const float a[4] = {av.x, av.y, av.z, av.w};
            const float b[4] = {bv.x, bv.y, bv.z, bv.w};
            #pragma unroll
            for (int ii = 0; ii < 4; ++ii)
                #pragma unroll
                for (int dd = 0; dd < 4; ++dd)
                    acc[ii][dd] = fmaf(a[ii], b[dd], acc[ii][dd]);
        }
    }

    // ---- epilogue: O = acc / l ----
    #pragma unroll
    for (int ii = 0; ii < 4; ++ii) {
        const float inv = 1.0f / lrow[ii];
        float4 o;
        o.x = acc[ii][0] * inv;
        o.y = acc[ii][1] * inv;
        o.z = acc[ii][2] * inv;
        o.w = acc[ii][3] * inv;
        *reinterpret_cast<float4*>(
            &O[(size_t)(q0 + ty*4 + ii) * DMODEL + h * DK + tx*4]) = o;
    }
}

// ---------------------------------------------------------------------------
extern "C" void kernel_launch(void* const* d_in, const int* in_sizes, int n_in,
                              void* d_out, int out_size, void* d_ws, size_t ws_size,
                              hipStream_t stream) {
    const float* x  = (const float*)d_in[0];
    const float* Wq = (const float*)d_in[1];
    const float* bq = (const float*)d_in[2];
    const float* Wk = (const float*)d_in[3];
    const float* bk = (const float*)d_in[4];
    const float* Wv = (const float*)d_in[5];
    const float* bv = (const float*)d_in[6];
    const float* Wo = (const float*)d_in[7];
    const float* bo = (const float*)d_in[8];
    float* out = (float*)d_out;

    const size_t planeN = (size_t)SEQ * DMODEL;   // 4M floats = 16 MB
    float* Qb = (float*)d_ws;
    float* Kb = Qb + planeN;
    float* Vb = Kb + planeN;
    float* Ob = Vb + planeN;                      // total 64 MB of d_ws

    const dim3 gGemm(DMODEL / 64, SEQ / 128);     // (16, 32)
    const dim3 block(256);

    gemm_nt_bias<<<gGemm, block, 0, stream>>>(x, Wq, bq, Qb, SEQ, DMODEL, DMODEL);
    gemm_nt_bias<<<gGemm, block, 0, stream>>>(x, Wk, bk, Kb, SEQ, DMODEL, DMODEL);
    gemm_nt_bias<<<gGemm, block, 0, stream>>>(x, Wv, bv, Vb, SEQ, DMODEL, DMODEL);

    const dim3 gAttn(SEQ / 64, NH);               // (64, 16)
    attn_causal<<<gAttn, block, 0, stream>>>(Qb, Kb, Vb, Ob);

    gemm_nt_bias<<<gGemm, block, 0, stream>>>(Ob, Wo, bo, out, SEQ, DMODEL, DMODEL);
}

// Round 2
// 839.211 us; speedup vs baseline: 3.5529x; 3.5529x over previous
//
#include <hip/hip_runtime.h>
#include <math.h>

#define SEQ 4096
#define DMODEL 1024
#define NH 16
#define DK 64
#define LDP 72   // padded LDS row length (bf16 elems): 144 B, 16B-aligned, 2-way banks

typedef __bf16 bf16x8 __attribute__((ext_vector_type(8)));
typedef float  f32x4  __attribute__((ext_vector_type(4)));

// ---------------------------------------------------------------------------
// GEMM: C[m][n] = sum_k A[m][k] * B[n][k] + bias[n]   (torch Linear: x @ W.T + b)
// fp32, BM=128 BN=64 BK=16, 256 threads, 8x4 per thread. (Unchanged from R1.)
// ---------------------------------------------------------------------------
__global__ __launch_bounds__(256)
void gemm_nt_bias(const float* __restrict__ A, const float* __restrict__ B,
                  const float* __restrict__ bias, float* __restrict__ C,
                  int M, int N, int K)
{
    __shared__ float As[16][132];
    __shared__ float Bs[16][68];

    const int t  = threadIdx.x;
    const int tx = t & 15;
    const int ty = t >> 4;
    const int m0 = blockIdx.y * 128;
    const int n0 = blockIdx.x * 64;

    float acc[8][4] = {};

    for (int k0 = 0; k0 < K; k0 += 16) {
        {
            int idx = t;
            #pragma unroll
            for (int p = 0; p < 2; ++p, idx += 256) {
                const int r = idx >> 2, c4 = idx & 3;
                const float4 v = *reinterpret_cast<const float4*>(
                    &A[(size_t)(m0 + r) * K + k0 + c4 * 4]);
                As[c4*4+0][r] = v.x;
                As[c4*4+1][r] = v.y;
                As[c4*4+2][r] = v.z;
                As[c4*4+3][r] = v.w;
            }
        }
        {
            const int r = t >> 2, c4 = t & 3;
            const float4 v = *reinterpret_cast<const float4*>(
                &B[(size_t)(n0 + r) * K + k0 + c4 * 4]);
            Bs[c4*4+0][r] = v.x;
            Bs[c4*4+1][r] = v.y;
            Bs[c4*4+2][r] = v.z;
            Bs[c4*4+3][r] = v.w;
        }
        __syncthreads();
        #pragma unroll
        for (int k = 0; k < 16; ++k) {
            const float4 a0 = *reinterpret_cast<const float4*>(&As[k][ty*8]);
            const float4 a1 = *reinterpret_cast<const float4*>(&As[k][ty*8+4]);
            const float4 bv = *reinterpret_cast<const float4*>(&Bs[k][tx*4]);
            const float a[8] = {a0.x,a0.y,a0.z,a0.w,a1.x,a1.y,a1.z,a1.w};
            const float b[4] = {bv.x,bv.y,bv.z,bv.w};
            #pragma unroll
            for (int i = 0; i < 8; ++i)
                #pragma unroll
                for (int j = 0; j < 4; ++j)
                    acc[i][j] = fmaf(a[i], b[j], acc[i][j]);
        }
        __syncthreads();
    }

    const float4 bb = *reinterpret_cast<const float4*>(&bias[n0 + tx*4]);
    #pragma unroll
    for (int i = 0; i < 8; ++i) {
        float4 o;
        o.x = acc[i][0] + bb.x;
        o.y = acc[i][1] + bb.y;
        o.z = acc[i][2] + bb.z;
        o.w = acc[i][3] + bb.w;
        *reinterpret_cast<float4*>(
            &C[(size_t)(m0 + ty*8 + i) * N + n0 + tx*4]) = o;
    }
}

// ---------------------------------------------------------------------------
// Causal flash attention via bf16 MFMA (16x16x32), fp32 accumulate.
// Block = 64 queries x 1 head, 4 waves; wave w owns queries [16w,16w+16).
// Layouts (all verified per cdna_hip_programming.md §3/m89/m120):
//   A-frag:  A[m=lane&15][k=quad*8+j]      -> row-major [m][k] LDS, b128 reads
//   B-frag:  B[k=quad*8+j][n=lane&15]      -> need [n][k] rows (K natural; V transposed)
//   C/D:     col=lane&15, row=quad*4+reg
// V is stored transposed [d][key] with key-chunk XOR swizzle (^ d>>3) so the
// scalar transpose-writes land on distinct banks (else 8-way conflicts).
// P goes C-layout -> wave-private LDS -> A-layout (no barrier: same-wave LDS
// is in-order; explicit lgkmcnt(0) drain before the re-read).
// ---------------------------------------------------------------------------
__global__ __launch_bounds__(256)
void attn_mfma(const float* __restrict__ Q, const float* __restrict__ K,
               const float* __restrict__ V, float* __restrict__ O)
{
    __shared__ __bf16 Qs[64][LDP];      // [query][d], Q pre-scaled by 0.125
    __shared__ __bf16 Ks[64][LDP];      // [key][d]
    __shared__ __bf16 VtF[64 * LDP];    // [d][key-swizzled]
    __shared__ __bf16 Ps[4][16][LDP];   // per-wave [q_local][key]

    const int t    = threadIdx.x;
    const int w    = t >> 6;
    const int lane = t & 63;
    const int l15  = lane & 15;
    const int quad = lane >> 4;
    const int h    = blockIdx.y;
    const int qtile = (int)gridDim.x - 1 - (int)blockIdx.x;  // heavy blocks first
    const int q0   = qtile * 64;

    // ---- stage Q (scaled; 0.125 is a power of two -> exact in bf16) ----
    #pragma unroll
    for (int p = 0; p < 2; ++p) {
        const int idx = t + p * 256;
        const int r = idx >> 3, c = (idx & 7) * 8;
        const size_t gb = (size_t)(q0 + r) * DMODEL + h * DK + c;
        const float4 f0 = *reinterpret_cast<const float4*>(&Q[gb]);
        const float4 f1 = *reinterpret_cast<const float4*>(&Q[gb + 4]);
        bf16x8 pk;
        pk[0] = (__bf16)(f0.x * 0.125f); pk[1] = (__bf16)(f0.y * 0.125f);
        pk[2] = (__bf16)(f0.z * 0.125f); pk[3] = (__bf16)(f0.w * 0.125f);
        pk[4] = (__bf16)(f1.x * 0.125f); pk[5] = (__bf16)(f1.y * 0.125f);
        pk[6] = (__bf16)(f1.z * 0.125f); pk[7] = (__bf16)(f1.w * 0.125f);
        *reinterpret_cast<bf16x8*>(&Qs[r][c]) = pk;
    }
    __syncthreads();
    const bf16x8 aq0 = *reinterpret_cast<const bf16x8*>(&Qs[w*16 + l15][quad*8]);
    const bf16x8 aq1 = *reinterpret_cast<const bf16x8*>(&Qs[w*16 + l15][32 + quad*8]);

    f32x4 acc[4] = {{0,0,0,0},{0,0,0,0},{0,0,0,0},{0,0,0,0}};
    float mrow[4] = {-INFINITY,-INFINITY,-INFINITY,-INFINITY};
    float lrow[4] = {0.f,0.f,0.f,0.f};

    for (int tk = 0; tk <= qtile; ++tk) {
        const int j0 = tk * 64;
        __syncthreads();   // all waves done reading Ks/VtF from previous tile
        #pragma unroll
        for (int p = 0; p < 2; ++p) {
            const int idx = t + p * 256;
            const int r = idx >> 3, c = (idx & 7) * 8;
            const size_t gb = (size_t)(j0 + r) * DMODEL + h * DK + c;
            const float4 f0 = *reinterpret_cast<const float4*>(&K[gb]);
            const float4 f1 = *reinterpret_cast<const float4*>(&K[gb + 4]);
            bf16x8 pk;
            pk[0] = (__bf16)f0.x; pk[1] = (__bf16)f0.y;
            pk[2] = (__bf16)f0.z; pk[3] = (__bf16)f0.w;
            pk[4] = (__bf16)f1.x; pk[5] = (__bf16)f1.y;
            pk[6] = (__bf16)f1.z; pk[7] = (__bf16)f1.w;
            *reinterpret_cast<bf16x8*>(&Ks[r][c]) = pk;

            const float4 g0 = *reinterpret_cast<const float4*>(&V[gb]);
            const float4 g1 = *reinterpret_cast<const float4*>(&V[gb + 4]);
            // transpose-store: V[key=r][d=c+j] -> VtF[d][swizzled key slot]
            const int slot = ((((r >> 3) ^ (c >> 3)) & 7) << 3) + (r & 7);
            VtF[(c + 0) * LDP + slot] = (__bf16)g0.x;
            VtF[(c + 1) * LDP + slot] = (__bf16)g0.y;
            VtF[(c + 2) * LDP + slot] = (__bf16)g0.z;
            VtF[(c + 3) * LDP + slot] = (__bf16)g0.w;
            VtF[(c + 4) * LDP + slot] = (__bf16)g1.x;
            VtF[(c + 5) * LDP + slot] = (__bf16)g1.y;
            VtF[(c + 6) * LDP + slot] = (__bf16)g1.z;
            VtF[(c + 7) * LDP + slot] = (__bf16)g1.w;
        }
        __syncthreads();

        // ---- S = Q*K^T : 4 key-subtiles of 16, 2 MFMA (k=0:32,32:64) each ----
        f32x4 sc[4];
        #pragma unroll
        for (int st = 0; st < 4; ++st) {
            const bf16x8 bk0 = *reinterpret_cast<const bf16x8*>(&Ks[st*16 + l15][quad*8]);
            const bf16x8 bk1 = *reinterpret_cast<const bf16x8*>(&Ks[st*16 + l15][32 + quad*8]);
            f32x4 cc = {0.f, 0.f, 0.f, 0.f};
            cc = __builtin_amdgcn_mfma_f32_16x16x32_bf16(aq0, bk0, cc, 0, 0, 0);
            cc = __builtin_amdgcn_mfma_f32_16x16x32_bf16(aq1, bk1, cc, 0, 0, 0);
            sc[st] = cc;
        }

        // ---- causal mask: only the diagonal tile needs it ----
        if (tk == qtile) {
            const int rloc = w * 16 + quad * 4;   // local query row base
            #pragma unroll
            for (int st = 0; st < 4; ++st)
                #pragma unroll
                for (int rg = 0; rg < 4; ++rg)
                    if (st * 16 + l15 > rloc + rg) sc[st][rg] = -INFINITY;
        }

        // ---- online softmax (row = quad*4+rg; 16 cols across lanes of quad) ----
        float alpha[4];
        #pragma unroll
        for (int rg = 0; rg < 4; ++rg) {
            float mx = fmaxf(fmaxf(sc[0][rg], sc[1][rg]), fmaxf(sc[2][rg], sc[3][rg]));
            mx = fmaxf(mx, __shfl_xor(mx, 1));
            mx = fmaxf(mx, __shfl_xor(mx, 2));
            mx = fmaxf(mx, __shfl_xor(mx, 4));
            mx = fmaxf(mx, __shfl_xor(mx, 8));
            const float mnew = fmaxf(mrow[rg], mx);   // finite: diagonal always visible
            const float al   = __expf(mrow[rg] - mnew);
            float rs = 0.f;
            #pragma unroll
            for (int st = 0; st < 4; ++st) {
                const float pv = __expf(sc[st][rg] - mnew);
                Ps[w][quad*4 + rg][st*16 + l15] = (__bf16)pv;
                rs += pv;
            }
            rs += __shfl_xor(rs, 1);
            rs += __shfl_xor(rs, 2);
            rs += __shfl_xor(rs, 4);
            rs += __shfl_xor(rs, 8);
            lrow[rg] = lrow[rg] * al + rs;
            mrow[rg] = mnew;
            alpha[rg] = al;
        }

        #pragma unroll
        for (int dst = 0; dst < 4; ++dst)
            #pragma unroll
            for (int rg = 0; rg < 4; ++rg)
                acc[dst][rg] *= alpha[rg];

        // drain the Ps writes before re-reading in A-layout (same wave, no barrier)
        asm volatile("s_waitcnt lgkmcnt(0)" ::: "memory");
        const bf16x8 ap0 = *reinterpret_cast<const bf16x8*>(&Ps[w][l15][quad*8]);
        const bf16x8 ap1 = *reinterpret_cast<const bf16x8*>(&Ps[w][l15][32 + quad*8]);

        // ---- O += P*V : 4 d-subtiles, 2 MFMA each ----
        #pragma unroll
        for (int dst = 0; dst < 4; ++dst) {
            const int d   = dst * 16 + l15;
            const int sw  = (d >> 3) & 7;
            const int ch0 = (quad)     ^ sw;   // k-step 0: key chunk 4*0+quad
            const int ch1 = (4 + quad) ^ sw;   // k-step 1: key chunk 4*1+quad
            const bf16x8 bv0 = *reinterpret_cast<const bf16x8*>(&VtF[d * LDP + ch0 * 8]);
            const bf16x8 bv1 = *reinterpret_cast<const bf16x8*>(&VtF[d * LDP + ch1 * 8]);
            acc[dst] = __builtin_amdgcn_mfma_f32_16x16x32_bf16(ap0, bv0, acc[dst], 0, 0, 0);
            acc[dst] = __builtin_amdgcn_mfma_f32_16x16x32_bf16(ap1, bv1, acc[dst], 0, 0, 0);
        }
    }

    // ---- epilogue: O = acc / l ----
    #pragma unroll
    for (int rg = 0; rg < 4; ++rg) {
        const float inv = 1.0f / lrow[rg];
        const size_t row = (size_t)(q0 + w*16 + quad*4 + rg) * DMODEL + h * DK;
        #pragma unroll
        for (int dst = 0; dst < 4; ++dst)
            O[row + dst*16 + l15] = acc[dst][rg] * inv;
    }
}

// ---------------------------------------------------------------------------
extern "C" void kernel_launch(void* const* d_in, const int* in_sizes, int n_in,
                              void* d_out, int out_size, void* d_ws, size_t ws_size,
                              hipStream_t stream) {
    const float* x  = (const float*)d_in[0];
    const float* Wq = (const float*)d_in[1];
    const float* bq = (const float*)d_in[2];
    const float* Wk = (const float*)d_in[3];
    const float* bk = (const float*)d_in[4];
    const float* Wv = (const float*)d_in[5];
    const float* bv = (const float*)d_in[6];
    const float* Wo = (const float*)d_in[7];
    const float* bo = (const float*)d_in[8];
    float* out = (float*)d_out;

    const size_t planeN = (size_t)SEQ * DMODEL;
    float* Qb = (float*)d_ws;
    float* Kb = Qb + planeN;
    float* Vb = Kb + planeN;
    float* Ob = Vb + planeN;   // 64 MB total

    const dim3 gGemm(DMODEL / 64, SEQ / 128);
    const dim3 block(256);

    gemm_nt_bias<<<gGemm, block, 0, stream>>>(x, Wq, bq, Qb, SEQ, DMODEL, DMODEL);
    gemm_nt_bias<<<gGemm, block, 0, stream>>>(x, Wk, bk, Kb, SEQ, DMODEL, DMODEL);
    gemm_nt_bias<<<gGemm, block, 0, stream>>>(x, Wv, bv, Vb, SEQ, DMODEL, DMODEL);

    const dim3 gAttn(SEQ / 64, NH);
    attn_mfma<<<gAttn, block, 0, stream>>>(Qb, Kb, Vb, Ob);

    gemm_nt_bias<<<gGemm, block, 0, stream>>>(Ob, Wo, bo, out, SEQ, DMODEL, DMODEL);
}

// Round 3
// 358.824 us; speedup vs baseline: 8.3094x; 2.3388x over previous
//
#include <hip/hip_runtime.h>
#include <math.h>

#define SEQ 4096
#define DMODEL 1024
#define NH 16
#define DK 64
#define LDP 72   // padded LDS row (bf16 elems): 144 B, keeps 16B alignment, 2-way banks (free)

typedef __bf16 bf16x8 __attribute__((ext_vector_type(8)));
typedef __bf16 bf16x4 __attribute__((ext_vector_type(4)));
typedef float  f32x4  __attribute__((ext_vector_type(4)));

// ---------------------------------------------------------------------------
// Convert x (4M) + Wq/Wk/Wv/Wo (1M each) fp32 -> bf16 into contiguous ws.
// ---------------------------------------------------------------------------
__global__ __launch_bounds__(256)
void cvt_all(const float* __restrict__ x, const float* __restrict__ Wq,
             const float* __restrict__ Wk, const float* __restrict__ Wv,
             const float* __restrict__ Wo, __bf16* __restrict__ dst)
{
    const size_t M1 = 1u << 20;
    const size_t e = ((size_t)blockIdx.x * 256 + threadIdx.x) * 8;
    const float* src; size_t off;
    if      (e < 4*M1) { src = x;  off = e;        }
    else if (e < 5*M1) { src = Wq; off = e - 4*M1; }
    else if (e < 6*M1) { src = Wk; off = e - 5*M1; }
    else if (e < 7*M1) { src = Wv; off = e - 6*M1; }
    else               { src = Wo; off = e - 7*M1; }
    const float4 f0 = *reinterpret_cast<const float4*>(&src[off]);
    const float4 f1 = *reinterpret_cast<const float4*>(&src[off + 4]);
    bf16x8 pk;
    pk[0]=(__bf16)f0.x; pk[1]=(__bf16)f0.y; pk[2]=(__bf16)f0.z; pk[3]=(__bf16)f0.w;
    pk[4]=(__bf16)f1.x; pk[5]=(__bf16)f1.y; pk[6]=(__bf16)f1.z; pk[7]=(__bf16)f1.w;
    *reinterpret_cast<bf16x8*>(&dst[e]) = pk;
}

// ---------------------------------------------------------------------------
// Shared bf16 MFMA GEMM core: C = A(MxK rm) * W(NxK rm)^T, tile 128x64, BK=64,
// 4 waves, wave w -> rows [w*32, w*32+32), acc[msub][nsub] f32x4.
// ---------------------------------------------------------------------------
__device__ __forceinline__ void gemm_core(const __bf16* __restrict__ A,
                                          const __bf16* __restrict__ W,
                                          int m0, int n0, int t,
                                          __bf16 (*As)[LDP], __bf16 (*Bs)[LDP],
                                          f32x4 acc[2][4])
{
    const int w = t >> 6, lane = t & 63, l15 = lane & 15, quad = lane >> 4;
    for (int k0 = 0; k0 < DMODEL; k0 += 64) {
        __syncthreads();
        #pragma unroll
        for (int p = 0; p < 4; ++p) {
            const int idx = t + p * 256;
            const int r = idx >> 3, c = (idx & 7) * 8;
            *reinterpret_cast<bf16x8*>(&As[r][c]) =
                *reinterpret_cast<const bf16x8*>(&A[(size_t)(m0 + r) * DMODEL + k0 + c]);
        }
        #pragma unroll
        for (int p = 0; p < 2; ++p) {
            const int idx = t + p * 256;
            const int r = idx >> 3, c = (idx & 7) * 8;
            *reinterpret_cast<bf16x8*>(&Bs[r][c]) =
                *reinterpret_cast<const bf16x8*>(&W[(size_t)(n0 + r) * DMODEL + k0 + c]);
        }
        __syncthreads();
        #pragma unroll
        for (int kb = 0; kb < 2; ++kb) {
            bf16x8 af0 = *reinterpret_cast<const bf16x8*>(&As[w*32 + l15][kb*32 + quad*8]);
            bf16x8 af1 = *reinterpret_cast<const bf16x8*>(&As[w*32 + 16 + l15][kb*32 + quad*8]);
            #pragma unroll
            for (int ns = 0; ns < 4; ++ns) {
                const bf16x8 bf_ = *reinterpret_cast<const bf16x8*>(&Bs[ns*16 + l15][kb*32 + quad*8]);
                acc[0][ns] = __builtin_amdgcn_mfma_f32_16x16x32_bf16(af0, bf_, acc[0][ns], 0, 0, 0);
                acc[1][ns] = __builtin_amdgcn_mfma_f32_16x16x32_bf16(af1, bf_, acc[1][ns], 0, 0, 0);
            }
        }
    }
}

// ---------------------------------------------------------------------------
// Fused Q/K/V projection. blockIdx.x: [0,16)=Q, [16,32)=K, [32,48)=V.
// Q written bf16 pre-scaled by 0.125*log2(e) (softmax base-2 trick);
// K written bf16 natural; V written bf16 TRANSPOSED per-column: Vt[n][s].
// ---------------------------------------------------------------------------
__global__ __launch_bounds__(256, 4)
void gemm_qkv(const __bf16* __restrict__ xb, const __bf16* __restrict__ Wqb,
              const __bf16* __restrict__ Wkb, const __bf16* __restrict__ Wvb,
              const float* __restrict__ bq, const float* __restrict__ bk,
              const float* __restrict__ bv,
              __bf16* __restrict__ Qb, __bf16* __restrict__ Kb, __bf16* __restrict__ Vtb)
{
    __shared__ __bf16 As[128][LDP];
    __shared__ __bf16 Bs[64][LDP];
    const int t = threadIdx.x;
    const int which = blockIdx.x >> 4;
    const int n0 = (blockIdx.x & 15) * 64;
    const int m0 = blockIdx.y * 128;
    const __bf16* W    = (which == 0) ? Wqb : (which == 1) ? Wkb : Wvb;
    const float*  bias = (which == 0) ? bq  : (which == 1) ? bk  : bv;

    f32x4 acc[2][4] = {};
    gemm_core(xb, W, m0, n0, t, As, Bs, acc);

    const int lane = t & 63, l15 = lane & 15, quad = lane >> 4, w = t >> 6;
    float br[4];
    #pragma unroll
    for (int ns = 0; ns < 4; ++ns) br[ns] = bias[n0 + ns*16 + l15];

    if (which == 2) {
        #pragma unroll
        for (int ms = 0; ms < 2; ++ms)
            #pragma unroll
            for (int ns = 0; ns < 4; ++ns) {
                bf16x4 pk;
                #pragma unroll
                for (int rg = 0; rg < 4; ++rg) pk[rg] = (__bf16)(acc[ms][ns][rg] + br[ns]);
                *reinterpret_cast<bf16x4*>(
                    &Vtb[(size_t)(n0 + ns*16 + l15) * SEQ + m0 + w*32 + ms*16 + quad*4]) = pk;
            }
    } else {
        const float s = (which == 0) ? 0.1803368787f : 1.0f;  // 0.125 * log2(e)
        __bf16* C = (which == 0) ? Qb : Kb;
        #pragma unroll
        for (int ms = 0; ms < 2; ++ms)
            #pragma unroll
            for (int ns = 0; ns < 4; ++ns)
                #pragma unroll
                for (int rg = 0; rg < 4; ++rg)
                    C[(size_t)(m0 + w*32 + ms*16 + quad*4 + rg) * DMODEL + n0 + ns*16 + l15] =
                        (__bf16)((acc[ms][ns][rg] + br[ns]) * s);
    }
}

// ---------------------------------------------------------------------------
// Output projection: fp32 result.
// ---------------------------------------------------------------------------
__global__ __launch_bounds__(256, 4)
void gemm_out(const __bf16* __restrict__ Ob, const __bf16* __restrict__ Wob,
              const float* __restrict__ bo, float* __restrict__ out)
{
    __shared__ __bf16 As[128][LDP];
    __shared__ __bf16 Bs[64][LDP];
    const int t = threadIdx.x;
    const int n0 = blockIdx.x * 64;
    const int m0 = blockIdx.y * 128;

    f32x4 acc[2][4] = {};
    gemm_core(Ob, Wob, m0, n0, t, As, Bs, acc);

    const int lane = t & 63, l15 = lane & 15, quad = lane >> 4, w = t >> 6;
    float br[4];
    #pragma unroll
    for (int ns = 0; ns < 4; ++ns) br[ns] = bo[n0 + ns*16 + l15];
    #pragma unroll
    for (int ms = 0; ms < 2; ++ms)
        #pragma unroll
        for (int ns = 0; ns < 4; ++ns)
            #pragma unroll
            for (int rg = 0; rg < 4; ++rg)
                out[(size_t)(m0 + w*32 + ms*16 + quad*4 + rg) * DMODEL + n0 + ns*16 + l15] =
                    acc[ms][ns][rg] + br[ns];
}

// ---------------------------------------------------------------------------
// Causal flash attention, bf16 MFMA, no-max (sum-only) softmax in base 2.
// Block = 128 q-rows x 1 head, 4 waves; wave w owns rows [w*32, w*32+32).
// Q pre-scaled so P = exp2(score). Scores bounded (|q.k|/8 small) -> safe.
// Per-lane partial row-sums; single cross-lane reduce at the end.
// ---------------------------------------------------------------------------
__global__ __launch_bounds__(256, 3)
void attn_mfma(const __bf16* __restrict__ Q, const __bf16* __restrict__ K,
               const __bf16* __restrict__ Vt, __bf16* __restrict__ O)
{
    __shared__ __bf16 Ks[64][LDP];       // [key][d]
    __shared__ __bf16 Vts[64][LDP];      // [d][key]  (from pre-transposed Vt)
    __shared__ __bf16 Ps[4][32][LDP];    // per-wave [q_local][key]

    const int t = threadIdx.x;
    const int w = t >> 6;
    const int lane = t & 63, l15 = lane & 15, quad = lane >> 4;
    const int h = blockIdx.y;
    const int qtile = (int)gridDim.x - 1 - (int)blockIdx.x;  // heavy blocks first
    const int q0 = qtile * 128;
    const int wrow0 = q0 + w * 32;

    // Q fragments straight from global (bf16, pre-scaled): 4 loads, once.
    bf16x8 aq[2][2];
    #pragma unroll
    for (int ms = 0; ms < 2; ++ms)
        #pragma unroll
        for (int kb = 0; kb < 2; ++kb)
            aq[ms][kb] = *reinterpret_cast<const bf16x8*>(
                &Q[(size_t)(wrow0 + ms*16 + l15) * DMODEL + h*DK + kb*32 + quad*8]);

    f32x4 acc[2][4] = {};    // [msub][dsub]
    float lsum[2][4] = {};   // [msub][rg] per-lane partial softmax denom

    const int ntiles = 2 * qtile + 2;
    for (int tk = 0; tk < ntiles; ++tk) {
        const int j0 = tk * 64;
        __syncthreads();   // all waves done reading Ks/Vts of previous tile
        #pragma unroll
        for (int p = 0; p < 2; ++p) {
            const int idx = t + p * 256;
            const int r = idx >> 3, c = (idx & 7) * 8;
            *reinterpret_cast<bf16x8*>(&Ks[r][c]) =
                *reinterpret_cast<const bf16x8*>(&K[(size_t)(j0 + r) * DMODEL + h*DK + c]);
            *reinterpret_cast<bf16x8*>(&Vts[r][c]) =
                *reinterpret_cast<const bf16x8*>(&Vt[(size_t)(h*DK + r) * SEQ + j0 + c]);
        }
        __syncthreads();

        if (j0 > wrow0 + 31) continue;   // wave fully masked (uniform branch, no barrier inside)

        // ---- scores (log2-domain): 4 key-subtiles, B-frags shared across msub ----
        f32x4 sc[2][4];
        #pragma unroll
        for (int st = 0; st < 4; ++st) {
            const bf16x8 bk0 = *reinterpret_cast<const bf16x8*>(&Ks[st*16 + l15][quad*8]);
            const bf16x8 bk1 = *reinterpret_cast<const bf16x8*>(&Ks[st*16 + l15][32 + quad*8]);
            #pragma unroll
            for (int ms = 0; ms < 2; ++ms) {
                f32x4 cc = {0.f, 0.f, 0.f, 0.f};
                cc = __builtin_amdgcn_mfma_f32_16x16x32_bf16(aq[ms][0], bk0, cc, 0, 0, 0);
                cc = __builtin_amdgcn_mfma_f32_16x16x32_bf16(aq[ms][1], bk1, cc, 0, 0, 0);
                sc[ms][st] = cc;
            }
        }

        // ---- P = exp2(score), causal mask, per-lane partial sums, write Ps ----
        const bool need_mask = (j0 + 63 > wrow0);
        #pragma unroll
        for (int ms = 0; ms < 2; ++ms)
            #pragma unroll
            for (int rg = 0; rg < 4; ++rg) {
                const int row = wrow0 + ms*16 + quad*4 + rg;
                #pragma unroll
                for (int st = 0; st < 4; ++st) {
                    float pv = exp2f(sc[ms][st][rg]);
                    if (need_mask && (j0 + st*16 + l15 > row)) pv = 0.f;
                    Ps[w][ms*16 + quad*4 + rg][st*16 + l15] = (__bf16)pv;
                    lsum[ms][rg] += pv;
                }
            }

        // drain Ps writes (same wave; no barrier needed)
        asm volatile("s_waitcnt lgkmcnt(0)" ::: "memory");

        // ---- PV: O += P * V ----
        bf16x8 ap[2][2];
        #pragma unroll
        for (int ms = 0; ms < 2; ++ms) {
            ap[ms][0] = *reinterpret_cast<const bf16x8*>(&Ps[w][ms*16 + l15][quad*8]);
            ap[ms][1] = *reinterpret_cast<const bf16x8*>(&Ps[w][ms*16 + l15][32 + quad*8]);
        }
        #pragma unroll
        for (int ds_ = 0; ds_ < 4; ++ds_) {
            const bf16x8 bv0 = *reinterpret_cast<const bf16x8*>(&Vts[ds_*16 + l15][quad*8]);
            const bf16x8 bv1 = *reinterpret_cast<const bf16x8*>(&Vts[ds_*16 + l15][32 + quad*8]);
            #pragma unroll
            for (int ms = 0; ms < 2; ++ms) {
                acc[ms][ds_] = __builtin_amdgcn_mfma_f32_16x16x32_bf16(ap[ms][0], bv0, acc[ms][ds_], 0, 0, 0);
                acc[ms][ds_] = __builtin_amdgcn_mfma_f32_16x16x32_bf16(ap[ms][1], bv1, acc[ms][ds_], 0, 0, 0);
            }
        }
    }

    // ---- final denom reduce (once) + store O bf16 ----
    #pragma unroll
    for (int ms = 0; ms < 2; ++ms)
        #pragma unroll
        for (int rg = 0; rg < 4; ++rg) {
            float s = lsum[ms][rg];
            s += __shfl_xor(s, 1);
            s += __shfl_xor(s, 2);
            s += __shfl_xor(s, 4);
            s += __shfl_xor(s, 8);
            lsum[ms][rg] = 1.0f / s;
        }
    #pragma unroll
    for (int ms = 0; ms < 2; ++ms)
        #pragma unroll
        for (int rg = 0; rg < 4; ++rg) {
            const size_t row = (size_t)(wrow0 + ms*16 + quad*4 + rg) * DMODEL + h * DK;
            #pragma unroll
            for (int ds_ = 0; ds_ < 4; ++ds_)
                O[row + ds_*16 + l15] = (__bf16)(acc[ms][ds_][rg] * lsum[ms][rg]);
        }
}

// ---------------------------------------------------------------------------
extern "C" void kernel_launch(void* const* d_in, const int* in_sizes, int n_in,
                              void* d_out, int out_size, void* d_ws, size_t ws_size,
                              hipStream_t stream) {
    const float* x  = (const float*)d_in[0];
    const float* Wq = (const float*)d_in[1];
    const float* bq = (const float*)d_in[2];
    const float* Wk = (const float*)d_in[3];
    const float* bk = (const float*)d_in[4];
    const float* Wv = (const float*)d_in[5];
    const float* bv = (const float*)d_in[6];
    const float* Wo = (const float*)d_in[7];
    const float* bo = (const float*)d_in[8];
    float* out = (float*)d_out;

    const size_t M1 = 1u << 20;
    __bf16* base = (__bf16*)d_ws;          // 24M bf16 = 48 MB total
    __bf16* xb  = base;                    // 4M
    __bf16* Wqb = base + 4*M1;             // 1M
    __bf16* Wkb = base + 5*M1;
    __bf16* Wvb = base + 6*M1;
    __bf16* Wob = base + 7*M1;
    __bf16* Qb  = base + 8*M1;             // 4M each
    __bf16* Kb  = base + 12*M1;
    __bf16* Vtb = base + 16*M1;
    __bf16* Ob  = base + 20*M1;

    cvt_all<<<4096, 256, 0, stream>>>(x, Wq, Wk, Wv, Wo, base);
    gemm_qkv<<<dim3(48, 32), 256, 0, stream>>>(xb, Wqb, Wkb, Wvb, bq, bk, bv, Qb, Kb, Vtb);
    attn_mfma<<<dim3(32, NH), 256, 0, stream>>>(Qb, Kb, Vtb, Ob);
    gemm_out<<<dim3(16, 32), 256, 0, stream>>>(Ob, Wob, bo, out);
}

// Round 4
// 305.329 us; speedup vs baseline: 9.7652x; 1.1752x over previous
//
#include <hip/hip_runtime.h>
#include <math.h>

#define SEQ 4096
#define DMODEL 1024
#define NH 16
#define DK 64
#define LDP 72   // padded LDS row (bf16 elems): 144 B, 16B-aligned, 2-way banks (free)

typedef __bf16 bf16x8 __attribute__((ext_vector_type(8)));
typedef __bf16 bf16x4 __attribute__((ext_vector_type(4)));
typedef float  f32x4  __attribute__((ext_vector_type(4)));

// ---------------------------------------------------------------------------
// Convert x (4M) + Wq/Wk/Wv/Wo (1M each) fp32 -> bf16 into contiguous ws.
// Order matters: Wq|Wk|Wv contiguous = the fused 3072x1024 QKV weight.
// ---------------------------------------------------------------------------
__global__ __launch_bounds__(256)
void cvt_all(const float* __restrict__ x, const float* __restrict__ Wq,
             const float* __restrict__ Wk, const float* __restrict__ Wv,
             const float* __restrict__ Wo, __bf16* __restrict__ dst)
{
    const size_t M1 = 1u << 20;
    const size_t e = ((size_t)blockIdx.x * 256 + threadIdx.x) * 8;
    const float* src; size_t off;
    if      (e < 4*M1) { src = x;  off = e;        }
    else if (e < 5*M1) { src = Wq; off = e - 4*M1; }
    else if (e < 6*M1) { src = Wk; off = e - 5*M1; }
    else if (e < 7*M1) { src = Wv; off = e - 6*M1; }
    else               { src = Wo; off = e - 7*M1; }
    const float4 f0 = *reinterpret_cast<const float4*>(&src[off]);
    const float4 f1 = *reinterpret_cast<const float4*>(&src[off + 4]);
    bf16x8 pk;
    pk[0]=(__bf16)f0.x; pk[1]=(__bf16)f0.y; pk[2]=(__bf16)f0.z; pk[3]=(__bf16)f0.w;
    pk[4]=(__bf16)f1.x; pk[5]=(__bf16)f1.y; pk[6]=(__bf16)f1.z; pk[7]=(__bf16)f1.w;
    *reinterpret_cast<bf16x8*>(&dst[e]) = pk;
}

// ---------------------------------------------------------------------------
// 128x128 GEMM core: C = A(MxK rm) * W(NxK rm)^T, BK=64, 4 waves in 2x2,
// each wave 64x64 = 4x4 MFMA subtiles. acc[msub][nsub].
// ---------------------------------------------------------------------------
__device__ __forceinline__ void gemm_core128(const __bf16* __restrict__ A,
                                             const __bf16* __restrict__ W,
                                             int m0, int n0, int t,
                                             __bf16 (*As)[LDP], __bf16 (*Bs)[LDP],
                                             f32x4 acc[4][4])
{
    const int w = t >> 6, lane = t & 63, l15 = lane & 15, quad = lane >> 4;
    const int wm = (w & 1) * 64, wn = (w >> 1) * 64;
    for (int k0 = 0; k0 < DMODEL; k0 += 64) {
        __syncthreads();
        #pragma unroll
        for (int p = 0; p < 4; ++p) {
            const int idx = t + p * 256;
            const int r = idx >> 3, c = (idx & 7) * 8;
            *reinterpret_cast<bf16x8*>(&As[r][c]) =
                *reinterpret_cast<const bf16x8*>(&A[(size_t)(m0 + r) * DMODEL + k0 + c]);
            *reinterpret_cast<bf16x8*>(&Bs[r][c]) =
                *reinterpret_cast<const bf16x8*>(&W[(size_t)(n0 + r) * DMODEL + k0 + c]);
        }
        __syncthreads();
        #pragma unroll
        for (int kb = 0; kb < 2; ++kb) {
            bf16x8 af[4], bfr[4];
            #pragma unroll
            for (int i = 0; i < 4; ++i) {
                af[i]  = *reinterpret_cast<const bf16x8*>(&As[wm + i*16 + l15][kb*32 + quad*8]);
                bfr[i] = *reinterpret_cast<const bf16x8*>(&Bs[wn + i*16 + l15][kb*32 + quad*8]);
            }
            #pragma unroll
            for (int ms = 0; ms < 4; ++ms)
                #pragma unroll
                for (int ns = 0; ns < 4; ++ns)
                    acc[ms][ns] = __builtin_amdgcn_mfma_f32_16x16x32_bf16(af[ms], bfr[ns], acc[ms][ns], 0, 0, 0);
        }
    }
}

// ---------------------------------------------------------------------------
// Fused QKV projection: one GEMM vs Wcat (3072x1024). Per-column-range
// epilogue: [0,1024)=Q (scaled 0.125*log2e), [1024,2048)=K, [2048,3072)=V
// written transposed Vt[d][s].
// ---------------------------------------------------------------------------
__global__ __launch_bounds__(256, 3)
void gemm_qkv(const __bf16* __restrict__ xb, const __bf16* __restrict__ Wcat,
              const float* __restrict__ bq, const float* __restrict__ bk,
              const float* __restrict__ bv,
              __bf16* __restrict__ Qb, __bf16* __restrict__ Kb, __bf16* __restrict__ Vtb)
{
    __shared__ __bf16 As[128][LDP];
    __shared__ __bf16 Bs[128][LDP];
    const int t = threadIdx.x;
    const int n0g = blockIdx.x * 128;          // global col in [0, 3072)
    const int m0  = blockIdx.y * 128;
    const int which = n0g >> 10;
    const int n_in  = n0g & 1023;

    f32x4 acc[4][4] = {};
    gemm_core128(xb, Wcat, m0, n0g, t, As, Bs, acc);

    const int w = t >> 6, lane = t & 63, l15 = lane & 15, quad = lane >> 4;
    const int wm = (w & 1) * 64, wn = (w >> 1) * 64;
    const float* bias = (which == 0) ? bq : (which == 1) ? bk : bv;
    float br[4];
    #pragma unroll
    for (int ns = 0; ns < 4; ++ns) br[ns] = bias[n_in + wn + ns*16 + l15];

    if (which == 2) {
        #pragma unroll
        for (int ms = 0; ms < 4; ++ms)
            #pragma unroll
            for (int ns = 0; ns < 4; ++ns) {
                bf16x4 pk;
                #pragma unroll
                for (int rg = 0; rg < 4; ++rg) pk[rg] = (__bf16)(acc[ms][ns][rg] + br[ns]);
                *reinterpret_cast<bf16x4*>(
                    &Vtb[(size_t)(n_in + wn + ns*16 + l15) * SEQ + m0 + wm + ms*16 + quad*4]) = pk;
            }
    } else {
        const float s = (which == 0) ? 0.1803368787f : 1.0f;  // 0.125 * log2(e)
        __bf16* C = (which == 0) ? Qb : Kb;
        #pragma unroll
        for (int ms = 0; ms < 4; ++ms)
            #pragma unroll
            for (int ns = 0; ns < 4; ++ns)
                #pragma unroll
                for (int rg = 0; rg < 4; ++rg)
                    C[(size_t)(m0 + wm + ms*16 + quad*4 + rg) * DMODEL + n_in + wn + ns*16 + l15] =
                        (__bf16)((acc[ms][ns][rg] + br[ns]) * s);
    }
}

// ---------------------------------------------------------------------------
// 128x64 GEMM core (known-good R3 path) for the output projection.
// ---------------------------------------------------------------------------
__device__ __forceinline__ void gemm_core64(const __bf16* __restrict__ A,
                                            const __bf16* __restrict__ W,
                                            int m0, int n0, int t,
                                            __bf16 (*As)[LDP], __bf16 (*Bs)[LDP],
                                            f32x4 acc[2][4])
{
    const int w = t >> 6, lane = t & 63, l15 = lane & 15, quad = lane >> 4;
    for (int k0 = 0; k0 < DMODEL; k0 += 64) {
        __syncthreads();
        #pragma unroll
        for (int p = 0; p < 4; ++p) {
            const int idx = t + p * 256;
            const int r = idx >> 3, c = (idx & 7) * 8;
            *reinterpret_cast<bf16x8*>(&As[r][c]) =
                *reinterpret_cast<const bf16x8*>(&A[(size_t)(m0 + r) * DMODEL + k0 + c]);
        }
        #pragma unroll
        for (int p = 0; p < 2; ++p) {
            const int idx = t + p * 256;
            const int r = idx >> 3, c = (idx & 7) * 8;
            *reinterpret_cast<bf16x8*>(&Bs[r][c]) =
                *reinterpret_cast<const bf16x8*>(&W[(size_t)(n0 + r) * DMODEL + k0 + c]);
        }
        __syncthreads();
        #pragma unroll
        for (int kb = 0; kb < 2; ++kb) {
            bf16x8 af0 = *reinterpret_cast<const bf16x8*>(&As[w*32 + l15][kb*32 + quad*8]);
            bf16x8 af1 = *reinterpret_cast<const bf16x8*>(&As[w*32 + 16 + l15][kb*32 + quad*8]);
            #pragma unroll
            for (int ns = 0; ns < 4; ++ns) {
                const bf16x8 bfr = *reinterpret_cast<const bf16x8*>(&Bs[ns*16 + l15][kb*32 + quad*8]);
                acc[0][ns] = __builtin_amdgcn_mfma_f32_16x16x32_bf16(af0, bfr, acc[0][ns], 0, 0, 0);
                acc[1][ns] = __builtin_amdgcn_mfma_f32_16x16x32_bf16(af1, bfr, acc[1][ns], 0, 0, 0);
            }
        }
    }
}

__global__ __launch_bounds__(256, 4)
void gemm_out(const __bf16* __restrict__ Ob, const __bf16* __restrict__ Wob,
              const float* __restrict__ bo, float* __restrict__ out)
{
    __shared__ __bf16 As[128][LDP];
    __shared__ __bf16 Bs[64][LDP];
    const int t = threadIdx.x;
    const int n0 = blockIdx.x * 64;
    const int m0 = blockIdx.y * 128;

    f32x4 acc[2][4] = {};
    gemm_core64(Ob, Wob, m0, n0, t, As, Bs, acc);

    const int lane = t & 63, l15 = lane & 15, quad = lane >> 4, w = t >> 6;
    float br[4];
    #pragma unroll
    for (int ns = 0; ns < 4; ++ns) br[ns] = bo[n0 + ns*16 + l15];
    #pragma unroll
    for (int ms = 0; ms < 2; ++ms)
        #pragma unroll
        for (int ns = 0; ns < 4; ++ns)
            #pragma unroll
            for (int rg = 0; rg < 4; ++rg)
                out[(size_t)(m0 + w*32 + ms*16 + quad*4 + rg) * DMODEL + n0 + ns*16 + l15] =
                    acc[ms][ns][rg] + br[ns];
}

// ---------------------------------------------------------------------------
// Causal flash attention, bf16 MFMA, sum-only base-2 softmax.
// LOAD-BALANCED: 64-row q-tiles; one block = paired q-tiles (qH=63-p, qL=p),
// waves 0-1 on qH, waves 2-3 on qL, sharing staged K/V. Every block does
// exactly 132 wave-tile units -> no triangular tail. p swizzled by head so
// co-resident blocks have different staging depth.
// ---------------------------------------------------------------------------
__global__ __launch_bounds__(256, 3)
void attn_mfma(const __bf16* __restrict__ Q, const __bf16* __restrict__ K,
               const __bf16* __restrict__ Vt, __bf16* __restrict__ O)
{
    __shared__ __bf16 Ks[64][LDP];       // [key][d]
    __shared__ __bf16 Vts[64][LDP];      // [d][key]
    __shared__ __bf16 Ps[4][32][LDP];    // per-wave [q_local][key]

    const int t = threadIdx.x;
    const int w = t >> 6;
    const int lane = t & 63, l15 = lane & 15, quad = lane >> 4;
    const int h = blockIdx.y;
    const int p = ((int)blockIdx.x + h) & 31;    // head-swizzled pair index
    const int qH = 63 - p, qL = p;
    const int wrow0 = (w < 2) ? qH * 64 + w * 32 : qL * 64 + (w - 2) * 32;

    // Q fragments (bf16, pre-scaled) straight from global, once.
    bf16x8 aq[2][2];
    #pragma unroll
    for (int ms = 0; ms < 2; ++ms)
        #pragma unroll
        for (int kb = 0; kb < 2; ++kb)
            aq[ms][kb] = *reinterpret_cast<const bf16x8*>(
                &Q[(size_t)(wrow0 + ms*16 + l15) * DMODEL + h*DK + kb*32 + quad*8]);

    f32x4 acc[2][4] = {};    // [msub][dsub]
    float lsum[2][4] = {};   // [msub][rg]

    const int ntiles = qH + 1;
    for (int tk = 0; tk < ntiles; ++tk) {
        const int j0 = tk * 64;
        __syncthreads();
        #pragma unroll
        for (int pp = 0; pp < 2; ++pp) {
            const int idx = t + pp * 256;
            const int r = idx >> 3, c = (idx & 7) * 8;
            *reinterpret_cast<bf16x8*>(&Ks[r][c]) =
                *reinterpret_cast<const bf16x8*>(&K[(size_t)(j0 + r) * DMODEL + h*DK + c]);
            *reinterpret_cast<bf16x8*>(&Vts[r][c]) =
                *reinterpret_cast<const bf16x8*>(&Vt[(size_t)(h*DK + r) * SEQ + j0 + c]);
        }
        __syncthreads();

        if (j0 > wrow0 + 31) continue;   // wave past its causal range (uniform)

        // ---- scores (log2 domain) ----
        f32x4 sc[2][4];
        #pragma unroll
        for (int st = 0; st < 4; ++st) {
            const bf16x8 bk0 = *reinterpret_cast<const bf16x8*>(&Ks[st*16 + l15][quad*8]);
            const bf16x8 bk1 = *reinterpret_cast<const bf16x8*>(&Ks[st*16 + l15][32 + quad*8]);
            #pragma unroll
            for (int ms = 0; ms < 2; ++ms) {
                f32x4 cc = {0.f, 0.f, 0.f, 0.f};
                cc = __builtin_amdgcn_mfma_f32_16x16x32_bf16(aq[ms][0], bk0, cc, 0, 0, 0);
                cc = __builtin_amdgcn_mfma_f32_16x16x32_bf16(aq[ms][1], bk1, cc, 0, 0, 0);
                sc[ms][st] = cc;
            }
        }

        // ---- P = exp2(score), causal mask, partial sums, Ps write ----
        const bool need_mask = (j0 + 63 > wrow0);
        #pragma unroll
        for (int ms = 0; ms < 2; ++ms)
            #pragma unroll
            for (int rg = 0; rg < 4; ++rg) {
                const int row = wrow0 + ms*16 + quad*4 + rg;
                #pragma unroll
                for (int st = 0; st < 4; ++st) {
                    float pv = exp2f(sc[ms][st][rg]);
                    if (need_mask && (j0 + st*16 + l15 > row)) pv = 0.f;
                    Ps[w][ms*16 + quad*4 + rg][st*16 + l15] = (__bf16)pv;
                    lsum[ms][rg] += pv;
                }
            }

        asm volatile("s_waitcnt lgkmcnt(0)" ::: "memory");  // same-wave Ps drain

        // ---- PV ----
        bf16x8 ap[2][2];
        #pragma unroll
        for (int ms = 0; ms < 2; ++ms) {
            ap[ms][0] = *reinterpret_cast<const bf16x8*>(&Ps[w][ms*16 + l15][quad*8]);
            ap[ms][1] = *reinterpret_cast<const bf16x8*>(&Ps[w][ms*16 + l15][32 + quad*8]);
        }
        #pragma unroll
        for (int ds_ = 0; ds_ < 4; ++ds_) {
            const bf16x8 bv0 = *reinterpret_cast<const bf16x8*>(&Vts[ds_*16 + l15][quad*8]);
            const bf16x8 bv1 = *reinterpret_cast<const bf16x8*>(&Vts[ds_*16 + l15][32 + quad*8]);
            #pragma unroll
            for (int ms = 0; ms < 2; ++ms) {
                acc[ms][ds_] = __builtin_amdgcn_mfma_f32_16x16x32_bf16(ap[ms][0], bv0, acc[ms][ds_], 0, 0, 0);
                acc[ms][ds_] = __builtin_amdgcn_mfma_f32_16x16x32_bf16(ap[ms][1], bv1, acc[ms][ds_], 0, 0, 0);
            }
        }
    }

    // ---- denom reduce + store ----
    #pragma unroll
    for (int ms = 0; ms < 2; ++ms)
        #pragma unroll
        for (int rg = 0; rg < 4; ++rg) {
            float s = lsum[ms][rg];
            s += __shfl_xor(s, 1);
            s += __shfl_xor(s, 2);
            s += __shfl_xor(s, 4);
            s += __shfl_xor(s, 8);
            lsum[ms][rg] = 1.0f / s;
        }
    #pragma unroll
    for (int ms = 0; ms < 2; ++ms)
        #pragma unroll
        for (int rg = 0; rg < 4; ++rg) {
            const size_t row = (size_t)(wrow0 + ms*16 + quad*4 + rg) * DMODEL + h * DK;
            #pragma unroll
            for (int ds_ = 0; ds_ < 4; ++ds_)
                O[row + ds_*16 + l15] = (__bf16)(acc[ms][ds_][rg] * lsum[ms][rg]);
        }
}

// ---------------------------------------------------------------------------
extern "C" void kernel_launch(void* const* d_in, const int* in_sizes, int n_in,
                              void* d_out, int out_size, void* d_ws, size_t ws_size,
                              hipStream_t stream) {
    const float* x  = (const float*)d_in[0];
    const float* Wq = (const float*)d_in[1];
    const float* bq = (const float*)d_in[2];
    const float* Wk = (const float*)d_in[3];
    const float* bk = (const float*)d_in[4];
    const float* Wv = (const float*)d_in[5];
    const float* bv = (const float*)d_in[6];
    const float* Wo = (const float*)d_in[7];
    const float* bo = (const float*)d_in[8];
    float* out = (float*)d_out;

    const size_t M1 = 1u << 20;
    __bf16* base = (__bf16*)d_ws;          // 24M bf16 = 48 MB total
    __bf16* xb   = base;                   // 4M
    __bf16* Wcat = base + 4*M1;            // Wq|Wk|Wv contiguous: 3M
    __bf16* Wob  = base + 7*M1;            // 1M
    __bf16* Qb   = base + 8*M1;            // 4M each
    __bf16* Kb   = base + 12*M1;
    __bf16* Vtb  = base + 16*M1;
    __bf16* Ob   = base + 20*M1;

    cvt_all<<<4096, 256, 0, stream>>>(x, Wq, Wk, Wv, Wo, base);
    gemm_qkv<<<dim3(24, 32), 256, 0, stream>>>(xb, Wcat, bq, bk, bv, Qb, Kb, Vtb);
    attn_mfma<<<dim3(32, NH), 256, 0, stream>>>(Qb, Kb, Vtb, Ob);
    gemm_out<<<dim3(16, 32), 256, 0, stream>>>(Ob, Wob, bo, out);
}

// Round 5
// 275.047 us; speedup vs baseline: 10.8403x; 1.1101x over previous
//
#include <hip/hip_runtime.h>
#include <math.h>

#define SEQ 4096
#define DMODEL 1024
#define NH 16
#define DK 64
#define LDP 72   // padded LDS row (16-bit elems): 144 B -> stride 36 banks (≡4 mod 32), conflict-free b64/b128

typedef __bf16    bf16x8 __attribute__((ext_vector_type(8)));
typedef __bf16    bf16x4 __attribute__((ext_vector_type(4)));
typedef float     f32x4  __attribute__((ext_vector_type(4)));
typedef _Float16  h16x4  __attribute__((ext_vector_type(4)));
typedef _Float16  h16x8  __attribute__((ext_vector_type(8)));

// ---------------------------------------------------------------------------
// Convert x (4M) + Wq/Wk/Wv/Wo (1M each) fp32 -> bf16 into contiguous ws.
// ---------------------------------------------------------------------------
__global__ __launch_bounds__(256)
void cvt_all(const float* __restrict__ x, const float* __restrict__ Wq,
             const float* __restrict__ Wk, const float* __restrict__ Wv,
             const float* __restrict__ Wo, __bf16* __restrict__ dst)
{
    const size_t M1 = 1u << 20;
    const size_t e = ((size_t)blockIdx.x * 256 + threadIdx.x) * 8;
    const float* src; size_t off;
    if      (e < 4*M1) { src = x;  off = e;        }
    else if (e < 5*M1) { src = Wq; off = e - 4*M1; }
    else if (e < 6*M1) { src = Wk; off = e - 5*M1; }
    else if (e < 7*M1) { src = Wv; off = e - 6*M1; }
    else               { src = Wo; off = e - 7*M1; }
    const float4 f0 = *reinterpret_cast<const float4*>(&src[off]);
    const float4 f1 = *reinterpret_cast<const float4*>(&src[off + 4]);
    bf16x8 pk;
    pk[0]=(__bf16)f0.x; pk[1]=(__bf16)f0.y; pk[2]=(__bf16)f0.z; pk[3]=(__bf16)f0.w;
    pk[4]=(__bf16)f1.x; pk[5]=(__bf16)f1.y; pk[6]=(__bf16)f1.z; pk[7]=(__bf16)f1.w;
    *reinterpret_cast<bf16x8*>(&dst[e]) = pk;
}

// ---------------------------------------------------------------------------
// 128x128 GEMM core: C = A(MxK rm) * W(NxK rm)^T, BK=64, 4 waves 2x2, 4x4 subtiles.
// ---------------------------------------------------------------------------
__device__ __forceinline__ void gemm_core128(const __bf16* __restrict__ A,
                                             const __bf16* __restrict__ W,
                                             int m0, int n0, int t,
                                             __bf16 (*As)[LDP], __bf16 (*Bs)[LDP],
                                             f32x4 acc[4][4])
{
    const int w = t >> 6, lane = t & 63, l15 = lane & 15, quad = lane >> 4;
    const int wm = (w & 1) * 64, wn = (w >> 1) * 64;
    for (int k0 = 0; k0 < DMODEL; k0 += 64) {
        __syncthreads();
        #pragma unroll
        for (int p = 0; p < 4; ++p) {
            const int idx = t + p * 256;
            const int r = idx >> 3, c = (idx & 7) * 8;
            *reinterpret_cast<bf16x8*>(&As[r][c]) =
                *reinterpret_cast<const bf16x8*>(&A[(size_t)(m0 + r) * DMODEL + k0 + c]);
            *reinterpret_cast<bf16x8*>(&Bs[r][c]) =
                *reinterpret_cast<const bf16x8*>(&W[(size_t)(n0 + r) * DMODEL + k0 + c]);
        }
        __syncthreads();
        #pragma unroll
        for (int kb = 0; kb < 2; ++kb) {
            bf16x8 af[4], bfr[4];
            #pragma unroll
            for (int i = 0; i < 4; ++i) {
                af[i]  = *reinterpret_cast<const bf16x8*>(&As[wm + i*16 + l15][kb*32 + quad*8]);
                bfr[i] = *reinterpret_cast<const bf16x8*>(&Bs[wn + i*16 + l15][kb*32 + quad*8]);
            }
            #pragma unroll
            for (int ms = 0; ms < 4; ++ms)
                #pragma unroll
                for (int ns = 0; ns < 4; ++ns)
                    acc[ms][ns] = __builtin_amdgcn_mfma_f32_16x16x32_bf16(af[ms], bfr[ns], acc[ms][ns], 0, 0, 0);
        }
    }
}

// ---------------------------------------------------------------------------
// Fused QKV projection -> fp16 outputs for the attention kernel.
// [0,1024)=Q scaled by 0.125*log2(e); [1024,2048)=K; [2048,3072)=V transposed Vt[d][s].
// ---------------------------------------------------------------------------
__global__ __launch_bounds__(256, 3)
void gemm_qkv(const __bf16* __restrict__ xb, const __bf16* __restrict__ Wcat,
              const float* __restrict__ bq, const float* __restrict__ bk,
              const float* __restrict__ bv,
              _Float16* __restrict__ Qh, _Float16* __restrict__ Kh, _Float16* __restrict__ Vth)
{
    __shared__ __bf16 As[128][LDP];
    __shared__ __bf16 Bs[128][LDP];
    const int t = threadIdx.x;
    const int n0g = blockIdx.x * 128;
    const int m0  = blockIdx.y * 128;
    const int which = n0g >> 10;
    const int n_in  = n0g & 1023;

    f32x4 acc[4][4] = {};
    gemm_core128(xb, Wcat, m0, n0g, t, As, Bs, acc);

    const int w = t >> 6, lane = t & 63, l15 = lane & 15, quad = lane >> 4;
    const int wm = (w & 1) * 64, wn = (w >> 1) * 64;
    const float* bias = (which == 0) ? bq : (which == 1) ? bk : bv;
    float br[4];
    #pragma unroll
    for (int ns = 0; ns < 4; ++ns) br[ns] = bias[n_in + wn + ns*16 + l15];

    if (which == 2) {
        #pragma unroll
        for (int ms = 0; ms < 4; ++ms)
            #pragma unroll
            for (int ns = 0; ns < 4; ++ns) {
                h16x4 pk;
                #pragma unroll
                for (int rg = 0; rg < 4; ++rg) pk[rg] = (_Float16)(acc[ms][ns][rg] + br[ns]);
                *reinterpret_cast<h16x4*>(
                    &Vth[(size_t)(n_in + wn + ns*16 + l15) * SEQ + m0 + wm + ms*16 + quad*4]) = pk;
            }
    } else {
        const float s = (which == 0) ? 0.1803368787f : 1.0f;  // 0.125 * log2(e)
        _Float16* C = (which == 0) ? Qh : Kh;
        #pragma unroll
        for (int ms = 0; ms < 4; ++ms)
            #pragma unroll
            for (int ns = 0; ns < 4; ++ns)
                #pragma unroll
                for (int rg = 0; rg < 4; ++rg)
                    C[(size_t)(m0 + wm + ms*16 + quad*4 + rg) * DMODEL + n_in + wn + ns*16 + l15] =
                        (_Float16)((acc[ms][ns][rg] + br[ns]) * s);
    }
}

// ---------------------------------------------------------------------------
// 128x64 GEMM core (known-good) for the output projection.
// ---------------------------------------------------------------------------
__device__ __forceinline__ void gemm_core64(const __bf16* __restrict__ A,
                                            const __bf16* __restrict__ W,
                                            int m0, int n0, int t,
                                            __bf16 (*As)[LDP], __bf16 (*Bs)[LDP],
                                            f32x4 acc[2][4])
{
    const int w = t >> 6, lane = t & 63, l15 = lane & 15, quad = lane >> 4;
    for (int k0 = 0; k0 < DMODEL; k0 += 64) {
        __syncthreads();
        #pragma unroll
        for (int p = 0; p < 4; ++p) {
            const int idx = t + p * 256;
            const int r = idx >> 3, c = (idx & 7) * 8;
            *reinterpret_cast<bf16x8*>(&As[r][c]) =
                *reinterpret_cast<const bf16x8*>(&A[(size_t)(m0 + r) * DMODEL + k0 + c]);
        }
        #pragma unroll
        for (int p = 0; p < 2; ++p) {
            const int idx = t + p * 256;
            const int r = idx >> 3, c = (idx & 7) * 8;
            *reinterpret_cast<bf16x8*>(&Bs[r][c]) =
                *reinterpret_cast<const bf16x8*>(&W[(size_t)(n0 + r) * DMODEL + k0 + c]);
        }
        __syncthreads();
        #pragma unroll
        for (int kb = 0; kb < 2; ++kb) {
            bf16x8 af0 = *reinterpret_cast<const bf16x8*>(&As[w*32 + l15][kb*32 + quad*8]);
            bf16x8 af1 = *reinterpret_cast<const bf16x8*>(&As[w*32 + 16 + l15][kb*32 + quad*8]);
            #pragma unroll
            for (int ns = 0; ns < 4; ++ns) {
                const bf16x8 bfr = *reinterpret_cast<const bf16x8*>(&Bs[ns*16 + l15][kb*32 + quad*8]);
                acc[0][ns] = __builtin_amdgcn_mfma_f32_16x16x32_bf16(af0, bfr, acc[0][ns], 0, 0, 0);
                acc[1][ns] = __builtin_amdgcn_mfma_f32_16x16x32_bf16(af1, bfr, acc[1][ns], 0, 0, 0);
            }
        }
    }
}

__global__ __launch_bounds__(256, 4)
void gemm_out(const __bf16* __restrict__ Ob, const __bf16* __restrict__ Wob,
              const float* __restrict__ bo, float* __restrict__ out)
{
    __shared__ __bf16 As[128][LDP];
    __shared__ __bf16 Bs[64][LDP];
    const int t = threadIdx.x;
    const int n0 = blockIdx.x * 64;
    const int m0 = blockIdx.y * 128;

    f32x4 acc[2][4] = {};
    gemm_core64(Ob, Wob, m0, n0, t, As, Bs, acc);

    const int lane = t & 63, l15 = lane & 15, quad = lane >> 4, w = t >> 6;
    float br[4];
    #pragma unroll
    for (int ns = 0; ns < 4; ++ns) br[ns] = bo[n0 + ns*16 + l15];
    #pragma unroll
    for (int ms = 0; ms < 2; ++ms)
        #pragma unroll
        for (int ns = 0; ns < 4; ++ns)
            #pragma unroll
            for (int rg = 0; rg < 4; ++rg)
                out[(size_t)(m0 + w*32 + ms*16 + quad*4 + rg) * DMODEL + n0 + ns*16 + l15] =
                    acc[ms][ns][rg] + br[ns];
}

// ---------------------------------------------------------------------------
// Score block for one 16-row q-slice: S^T = K_tile . Q^T via 16x16x16 f16 MFMA,
// then P = exp2(S^T) packed DIRECTLY into the A-fragment for PV (C-layout of
// S^T == A-layout of next MFMA: lane l15=q, regs = keys quad*4+rg).
// ---------------------------------------------------------------------------
__device__ __forceinline__ void score16(const h16x4 (&ak)[4][4], const h16x4 (&bq)[4],
                                        bool msk, int lhs /*w*16+l15*/, int quad4,
                                        float& lsum, h16x4 (&apf)[4])
{
    #pragma unroll
    for (int st = 0; st < 4; ++st) {
        f32x4 cc = {0.f, 0.f, 0.f, 0.f};
        #pragma unroll
        for (int kb = 0; kb < 4; ++kb)
            cc = __builtin_amdgcn_mfma_f32_16x16x16f16(ak[st][kb], bq[kb], cc, 0, 0, 0);
        #pragma unroll
        for (int rg = 0; rg < 4; ++rg) {
            float pv = exp2f(cc[rg]);
            if (msk && (st*16 + quad4 + rg > lhs)) pv = 0.f;
            lsum += pv;
            apf[st][rg] = (_Float16)pv;
        }
    }
}

// ---------------------------------------------------------------------------
// Causal flash attention, fp16 MFMA 16x16x16, sum-only base-2 softmax, P kept
// in registers (no LDS round-trip). Block = paired 64-row q-tiles (qH=63-p,
// qL=p); ALL 4 waves work every iteration: wave w owns 16-row slice of the
// heavy tile (always) + of the light tile (while tk<=qL). K/V frags shared
// across the two slices.
// ---------------------------------------------------------------------------
__global__ __launch_bounds__(256, 3)
void attn_mfma(const _Float16* __restrict__ Q, const _Float16* __restrict__ K,
               const _Float16* __restrict__ Vt, __bf16* __restrict__ O)
{
    __shared__ _Float16 Ks[64][LDP];     // [key][d]
    __shared__ _Float16 Vts[64][LDP];    // [d][key]

    const int t = threadIdx.x;
    const int w = t >> 6;
    const int lane = t & 63, l15 = lane & 15, quad = lane >> 4;
    const int h = blockIdx.y;
    const int p = ((int)blockIdx.x + h) & 31;    // head-swizzled pair index
    const int qH = 63 - p, qL = p;
    int sb[2]; sb[0] = qH*64 + w*16; sb[1] = qL*64 + w*16;
    const int lhs = w*16 + l15;

    // Q B-frags (B[k=d][n=q]: lane n=l15 holds d=quad*4+j), preloaded once.
    h16x4 bq_[2][4];
    #pragma unroll
    for (int s = 0; s < 2; ++s)
        #pragma unroll
        for (int kb = 0; kb < 4; ++kb)
            bq_[s][kb] = *reinterpret_cast<const h16x4*>(
                &Q[(size_t)(sb[s] + l15) * DMODEL + h*DK + kb*16 + quad*4]);

    f32x4 acc[2][4] = {};        // [slice][dsub]; C-layout: col=d=l15, row=q=quad*4+rg
    float lsum[2] = {0.f, 0.f};  // per-lane: denom partial for q-row l15 of slice

    for (int tk = 0; tk <= qH; ++tk) {
        const int j0 = tk * 64;
        __syncthreads();
        #pragma unroll
        for (int pp = 0; pp < 2; ++pp) {
            const int idx = t + pp * 256;
            const int r = idx >> 3, c = (idx & 7) * 8;
            *reinterpret_cast<h16x8*>(&Ks[r][c]) =
                *reinterpret_cast<const h16x8*>(&K[(size_t)(j0 + r) * DMODEL + h*DK + c]);
            *reinterpret_cast<h16x8*>(&Vts[r][c]) =
                *reinterpret_cast<const h16x8*>(&Vt[(size_t)(h*DK + r) * SEQ + j0 + c]);
        }
        __syncthreads();

        // K A-frags (A[m=key][k=d]: lane m=l15 holds d=quad*4+j), shared by both slices.
        h16x4 ak[4][4];
        #pragma unroll
        for (int st = 0; st < 4; ++st)
            #pragma unroll
            for (int kb = 0; kb < 4; ++kb)
                ak[st][kb] = *reinterpret_cast<const h16x4*>(&Ks[st*16 + l15][kb*16 + quad*4]);

        const bool two = (tk <= qL);
        h16x4 ap0[4], ap1[4];
        score16(ak, bq_[0], tk == qH, lhs, quad*4, lsum[0], ap0);
        if (two) score16(ak, bq_[1], tk == qL, lhs, quad*4, lsum[1], ap1);

        // PV: O^ += P.V ; B[k=key][n=d]: lane n=l15 holds keys quad*4+j from Vts.
        #pragma unroll
        for (int ds_ = 0; ds_ < 4; ++ds_)
            #pragma unroll
            for (int st = 0; st < 4; ++st) {
                const h16x4 bv = *reinterpret_cast<const h16x4*>(&Vts[ds_*16 + l15][st*16 + quad*4]);
                acc[0][ds_] = __builtin_amdgcn_mfma_f32_16x16x16f16(ap0[st], bv, acc[0][ds_], 0, 0, 0);
                if (two)
                    acc[1][ds_] = __builtin_amdgcn_mfma_f32_16x16x16f16(ap1[st], bv, acc[1][ds_], 0, 0, 0);
            }
    }

    // ---- denom: reduce across quads (lane l15 holds row-l15 partial) ----
    #pragma unroll
    for (int s = 0; s < 2; ++s) {
        float ls = lsum[s];
        ls += __shfl_xor(ls, 16);
        ls += __shfl_xor(ls, 32);
        #pragma unroll
        for (int rg = 0; rg < 4; ++rg) {
            const float dn = __shfl(ls, quad*4 + rg);   // denom of q-row quad*4+rg
            const float inv = 1.0f / dn;
            const size_t row = (size_t)(sb[s] + quad*4 + rg) * DMODEL + h * DK;
            #pragma unroll
            for (int ds_ = 0; ds_ < 4; ++ds_)
                O[row + ds_*16 + l15] = (__bf16)(acc[s][ds_][rg] * inv);
        }
    }
}

// ---------------------------------------------------------------------------
extern "C" void kernel_launch(void* const* d_in, const int* in_sizes, int n_in,
                              void* d_out, int out_size, void* d_ws, size_t ws_size,
                              hipStream_t stream) {
    const float* x  = (const float*)d_in[0];
    const float* Wq = (const float*)d_in[1];
    const float* bq = (const float*)d_in[2];
    const float* Wk = (const float*)d_in[3];
    const float* bk = (const float*)d_in[4];
    const float* Wv = (const float*)d_in[5];
    const float* bv = (const float*)d_in[6];
    const float* Wo = (const float*)d_in[7];
    const float* bo = (const float*)d_in[8];
    float* out = (float*)d_out;

    const size_t M1 = 1u << 20;
    __bf16* base = (__bf16*)d_ws;          // 24M 16-bit elems = 48 MB
    __bf16*    xb   = base;                // 4M bf16
    __bf16*    Wcat = base + 4*M1;         // Wq|Wk|Wv contiguous (3M bf16)
    __bf16*    Wob  = base + 7*M1;         // 1M bf16
    _Float16*  Qh   = (_Float16*)(base + 8*M1);    // 4M fp16 each
    _Float16*  Kh   = (_Float16*)(base + 12*M1);
    _Float16*  Vth  = (_Float16*)(base + 16*M1);
    __bf16*    Ob   = base + 20*M1;        // 4M bf16

    cvt_all<<<4096, 256, 0, stream>>>(x, Wq, Wk, Wv, Wo, base);
    gemm_qkv<<<dim3(24, 32), 256, 0, stream>>>(xb, Wcat, bq, bk, bv, Qh, Kh, Vth);
    attn_mfma<<<dim3(32, NH), 256, 0, stream>>>(Qh, Kh, Vth, Ob);
    gemm_out<<<dim3(16, 32), 256, 0, stream>>>(Ob, Wob, bo, out);
}